// Round 2
// baseline (257.435 us; speedup 1.0000x reference)
//
#include <hip/hip_runtime.h>

// Tensor Fusion Network, MI355X. Round 4.
// k1: fusion[b][p] bf16 via per-wave MFMA; NEW: register-accumulated output
//     tile -> LDS transpose (wave-private, no barrier) -> fully coalesced
//     dwordx4 global stores (wave tile = contiguous 3104B in fusion).
//     Incremental (i,j) (no per-ijl integer div). v_s stored bf16 to fit LDS.
// k2: split-K GEMM; NEW: 2-deep W1 prefetch pipeline (unroll-by-2, static reg
//     sets) -> PACKW waits on loads issued a full step earlier => ~no vmcnt
//     stall, HBM duty ~100%. Fixed 16 steps (guards make phantom work exact).
// k3: parallel reduce + bias + relu (512 thr).
// k4: fused MLP tail.

#define B_    128
#define T_    64
#define A1    49
#define V1    49
#define X1    97
#define IJ    2401      // 49*49
#define KTOT  232897    // IJ*97
#define FP    232928    // KTOT padded to multiple of 32
#define PF    128
#define KC    512
#define NB2   455       // ceil(FP/KC)

typedef short s8v __attribute__((ext_vector_type(8)));   // 8 bf16
typedef float f4v __attribute__((ext_vector_type(4)));   // 4 fp32

__device__ __forceinline__ unsigned short f2bf(float f) {
    union { float f; unsigned u; } v; v.f = f;
    return (unsigned short)((v.u + 0x7FFFu + ((v.u >> 16) & 1u)) >> 16); // RNE
}
__device__ __forceinline__ float bf2f(unsigned short h) {
    union { unsigned u; float f; } v; v.u = ((unsigned)h) << 16;
    return v.f;
}

// ---------------- k1: fusion (bf16) -------------------------------------
// grid (4, 128): blockIdx.y = b, blockIdx.x covers 38 ij-tiles of 16 (151 total).
// 512 threads = 8 waves; each wave owns a private 3104B slice in LDS used first
// as the w-operand [16 ij][72 t] then as the output tile [16 ij][97 k].
__global__ __launch_bounds__(512) void k1_fusion(
    const float* __restrict__ audio, const float* __restrict__ video,
    const float* __restrict__ text, unsigned short* __restrict__ fusion)
{
    __shared__ float a_s[T_ * A1];                 // [t][i] f32   12544 B
    __shared__ unsigned short v_s[T_ * V1];        // [t][j] bf16   6272 B
    __shared__ unsigned short xT[112 * 72];        // [k][t] pad72 16128 B
    __shared__ unsigned short w_ws[8][1552];       // per-wave slice 3104 B

    const int b = blockIdx.y;
    const int bx = blockIdx.x;
    const int tid = threadIdx.x;

    for (int idx = tid; idx < T_ * A1; idx += 512) {
        int t = idx / 49, i = idx - t * 49;
        a_s[idx] = (i == 0) ? 1.0f : audio[(b * T_ + t) * 48 + (i - 1)];
        v_s[idx] = f2bf((i == 0) ? 1.0f : video[(b * T_ + t) * 48 + (i - 1)]);
    }
    for (int idx = tid; idx < T_ * X1; idx += 512) {
        int t = idx / 97, k = idx - t * 97;
        xT[k * 72 + t] = f2bf((k == 0) ? 1.0f : text[(b * T_ + t) * 96 + (k - 1)]);
    }
    for (int idx = tid; idx < 15 * 64; idx += 512) {   // zero pad rows k=97..111
        xT[(97 + (idx >> 6)) * 72 + (idx & 63)] = 0;
    }
    if (bx == 0) {                                      // zero fusion pad [KTOT,FP)
        for (int idx = tid; idx < FP - KTOT; idx += 512)
            fusion[(size_t)b * FP + KTOT + idx] = 0;
    }
    __syncthreads();

    const int wave = tid >> 6, lane = tid & 63;
    const int q = lane >> 4, ln = lane & 15;
    unsigned short* w_s = w_ws[wave];

    for (int it = 0; it < 5; ++it) {
        const int tw = it * 8 + wave;          // tile-within-x-block
        if (tw >= 38) break;                   // wave-uniform
        const int tl = bx * 38 + tw;           // global 16-ij tile
        if (tl >= 151) break;
        const int ij0 = tl * 16;

        // w-compute: lane = t, loop over 16 local ij; incremental (i,j)
        {
            int i = ij0 / 49, j = ij0 - (ij0 / 49) * 49;
            #pragma unroll
            for (int ijl = 0; ijl < 16; ++ijl) {
                unsigned short wv = 0;
                if (ij0 + ijl < IJ)
                    wv = f2bf(a_s[lane * 49 + i] * bf2f(v_s[lane * 49 + j]));
                w_s[ijl * 72 + lane] = wv;
                if (++j == 49) { j = 0; ++i; }
            }
        }
        // A-frags: lane holds A[m=ln][t = q*8 + 0..7 (+32)]
        s8v af0 = *(const s8v*)&w_s[ln * 72 + q * 8];
        s8v af1 = *(const s8v*)&w_s[ln * 72 + 32 + q * 8];

        f4v pacc[7];
        #pragma unroll
        for (int nt = 0; nt < 7; ++nt) {
            s8v bf0 = *(const s8v*)&xT[(nt * 16 + ln) * 72 + q * 8];
            s8v bf1 = *(const s8v*)&xT[(nt * 16 + ln) * 72 + 32 + q * 8];
            f4v acc = {0.f, 0.f, 0.f, 0.f};
            acc = __builtin_amdgcn_mfma_f32_16x16x32_bf16(af0, bf0, acc, 0, 0, 0);
            acc = __builtin_amdgcn_mfma_f32_16x16x32_bf16(af1, bf1, acc, 0, 0, 0);
            pacc[nt] = acc;
        }

        // transpose to packed [16 ij][97 k] in the SAME slice (frag data is in
        // regs; writes depend on pacc -> ordered after the reads above).
        #pragma unroll
        for (int nt = 0; nt < 7; ++nt) {
            int kk = nt * 16 + ln;             // C: col=ln -> k, row=q*4+r -> ij
            if (kk < X1) {
                #pragma unroll
                for (int r = 0; r < 4; ++r)
                    w_s[(q * 4 + r) * 97 + kk] = f2bf(pacc[nt][r]);
            }
        }
        asm volatile("s_waitcnt lgkmcnt(0)" ::: "memory");
        __builtin_amdgcn_sched_barrier(0);

        // coalesced copy-out: wave tile = contiguous bytes in fusion.
        // last tile (nv=1): 13 chunks copy 208B >= 194B valid; the 14B overrun
        // lands in the [KTOT,FP) pad, which k2 multiplies by W1-guard zeros.
        const int nv = min(16, IJ - ij0);
        const int bytes = nv * 194;            // nv*97*2
        char* gdst = (char*)(fusion + (size_t)b * FP + (size_t)ij0 * 97);
        const char* lsrc = (const char*)w_s;
        for (int off = lane * 16; off < bytes; off += 1024) {
            uint4 d = *(const uint4*)(lsrc + off);
            *(uint4*)(gdst + off) = d;
        }
    }
}

// ---------------- k2: split-K GEMM h1-partials --------------------------
// 512 threads = 8 waves; wave w owns b-rows [16w, 16w+16). A-frags straight
// from global. W1 staged bf16 in double-buffered LDS with a 2-deep prefetch:
// at PACKW time the awaited loads are a full step old -> ~no vmcnt stall.
#define BPAD 40   // LDS row pad (elements)
__global__ __launch_bounds__(512) void k2_gemm(
    const unsigned short* __restrict__ fusion, const float* __restrict__ W1,
    float* __restrict__ partials)
{
    __shared__ unsigned short B_l[2][128 * BPAD];  // [f][p_local], 2 buffers

    const int blk = blockIdx.x;
    const int kbase = blk * KC;
    const int tid = threadIdx.x;
    const int wave = tid >> 6, lane = tid & 63;
    const int q = lane >> 4, ln = lane & 15;
    const int fB = tid & 127, g = tid >> 7;    // B-stage: thread -> (f, 8-p group)

    const unsigned short* Arow =
        fusion + (size_t)(wave * 16 + ln) * FP + kbase + q * 8;

    f4v acc[8];
    #pragma unroll
    for (int n = 0; n < 8; ++n) acc[n] = (f4v){0.f, 0.f, 0.f, 0.f};

#define LOADW(dst, s)                                                       \
    {                                                                       \
        _Pragma("unroll")                                                   \
        for (int c = 0; c < 8; ++c) {                                       \
            int p = kbase + (s) * 32 + g * 8 + c;                           \
            dst[c] = (p < KTOT) ? W1[(size_t)p * PF + fB] : 0.f;            \
        }                                                                   \
    }
#define PACKW(src, buf)                                                     \
    {                                                                       \
        ushort4 lo, hi;                                                     \
        lo.x = f2bf(src[0]); lo.y = f2bf(src[1]);                           \
        lo.z = f2bf(src[2]); lo.w = f2bf(src[3]);                           \
        hi.x = f2bf(src[4]); hi.y = f2bf(src[5]);                           \
        hi.z = f2bf(src[6]); hi.w = f2bf(src[7]);                           \
        *(ushort4*)&B_l[buf][fB * BPAD + g * 8]     = lo;                   \
        *(ushort4*)&B_l[buf][fB * BPAD + g * 8 + 4] = hi;                   \
    }
#define MFMA8(av, buf)                                                      \
    {                                                                       \
        _Pragma("unroll")                                                   \
        for (int nt = 0; nt < 8; ++nt) {                                    \
            s8v bfv = *(const s8v*)&B_l[buf][(nt * 16 + ln) * BPAD + q * 8];\
            acc[nt] = __builtin_amdgcn_mfma_f32_16x16x32_bf16(              \
                av, bfv, acc[nt], 0, 0, 0);                                 \
        }                                                                   \
    }

    float w0[8], w1[8];
    s8v a0v, a1v;

    // prologue: buf0 <- W(0); issue W(1), A(0)
    LOADW(w0, 0);
    PACKW(w0, 0);
    LOADW(w1, 1);
    a0v = *(const s8v*)Arow;
    __syncthreads();

    // 16 steps, unrolled by 2. Fixed trip count for ALL blocks: the p<KTOT
    // guard zeros phantom W1 columns; phantom A-reads stay inside the
    // workspace (fusion pad / partials) and multiply by those zeros.
    for (int i = 0; i < 8; ++i) {
        const bool more = (i < 7);             // wave-uniform
        // -- even step s=2i: consume buf0 with A=a0v
        if (more) LOADW(w0, 2 * i + 2);
        a1v = *(const s8v*)(Arow + (2 * i + 1) * 32);
        MFMA8(a0v, 0);
        PACKW(w1, 1);
        __syncthreads();
        // -- odd step s=2i+1: consume buf1 with A=a1v
        if (more) {
            LOADW(w1, 2 * i + 3);
            a0v = *(const s8v*)(Arow + (2 * i + 2) * 32);
        }
        MFMA8(a1v, 1);
        if (more) {
            PACKW(w0, 0);
            __syncthreads();
        }
    }
#undef LOADW
#undef PACKW
#undef MFMA8

    float* outp = partials + (size_t)blk * (128 * 128);
    #pragma unroll
    for (int nt = 0; nt < 8; ++nt) {
        const int f = nt * 16 + ln;
        #pragma unroll
        for (int r = 0; r < 4; ++r)
            outp[(wave * 16 + q * 4 + r) * 128 + f] = acc[nt][r];
    }
}

// ---------------- k3: reduce partials + bias + relu ---------------------
// grid 256 blocks x 512 thr: block owns 64 e-values, 8-way r-split per e.
__global__ __launch_bounds__(512) void k3_reduce(
    const float* __restrict__ partials, const float* __restrict__ b1,
    float* __restrict__ h1)
{
    __shared__ float red[512];
    const int e = blockIdx.x * 64 + (threadIdx.x & 63);
    const int rh = threadIdx.x >> 6;           // 0..7
    float s = 0.f;
    for (int r = rh; r < NB2; r += 8)
        s += partials[(size_t)r * 16384 + e];
    red[threadIdx.x] = s;
    __syncthreads();
    if (threadIdx.x < 64) {
        float v = 0.f;
        #pragma unroll
        for (int j = 0; j < 8; ++j) v += red[threadIdx.x + 64 * j];
        v += b1[e & 127];
        h1[e] = fmaxf(v, 0.f);
    }
}

// ---------------- k4: h2 = relu(h1@W2+b2); out = sigmoid(h2@W3+b3)*6-3 --
__global__ __launch_bounds__(128) void k4_out(
    const float* __restrict__ h1, const float* __restrict__ W2,
    const float* __restrict__ b2, const float* __restrict__ W3,
    const float* __restrict__ b3, float* __restrict__ out)
{
    __shared__ float hrow[128];
    __shared__ float red2[2];
    const int b = blockIdx.x, f = threadIdx.x;
    hrow[f] = h1[b * 128 + f];
    __syncthreads();
    float s = b2[f];
    #pragma unroll 8
    for (int c = 0; c < 128; ++c) s += hrow[c] * W2[c * 128 + f];
    float p = fmaxf(s, 0.f) * W3[f];
    #pragma unroll
    for (int off = 32; off; off >>= 1) p += __shfl_down(p, off, 64);
    if ((f & 63) == 0) red2[f >> 6] = p;
    __syncthreads();
    if (f == 0) {
        float t = red2[0] + red2[1] + b3[0];
        out[b] = 6.0f / (1.0f + expf(-t)) - 3.0f;
    }
}

extern "C" void kernel_launch(void* const* d_in, const int* in_sizes, int n_in,
                              void* d_out, int out_size, void* d_ws, size_t ws_size,
                              hipStream_t stream)
{
    const float* audio = (const float*)d_in[0];
    const float* video = (const float*)d_in[1];
    const float* text  = (const float*)d_in[2];
    const float* W1 = (const float*)d_in[3];
    const float* b1 = (const float*)d_in[4];
    const float* W2 = (const float*)d_in[5];
    const float* b2 = (const float*)d_in[6];
    const float* W3 = (const float*)d_in[7];
    const float* b3 = (const float*)d_in[8];
    float* out = (float*)d_out;

    // ws layout: fusion bf16 [128][FP] = 59,629,568 B
    //            partials fp32 [455][16384] = 29,818,880 B @ 59,629,568
    //            h1 @ 89,448,448 ; total 89,513,984 B
    char* ws = (char*)d_ws;
    unsigned short* fusion = (unsigned short*)ws;
    float* partials = (float*)(ws + 59629568);
    float* h1 = (float*)(ws + 89448448);

    k1_fusion<<<dim3(4, 128), 512, 0, stream>>>(audio, video, text, fusion);
    k2_gemm<<<dim3(NB2), 512, 0, stream>>>(fusion, W1, partials);
    k3_reduce<<<dim3(256), 512, 0, stream>>>(partials, b1, h1);
    k4_out<<<dim3(128), 128, 0, stream>>>(h1, W2, b2, W3, b3, out);
}

// Round 3
// 247.513 us; speedup vs baseline: 1.0401x; 1.0401x over previous
//
#include <hip/hip_runtime.h>

// Tensor Fusion Network, MI355X. Round 5.
// k1: fusion[b][p] bf16 via per-wave MFMA (unchanged from round 4).
// k2: split-K GEMM; NEW chunking KC=928, 251 blocks (251*928 = FP exactly):
//     perfect CU balance (1 block/CU), no phantom tail steps, partials
//     shrunk 29.8 -> 16.4 MB. 2-deep W1 prefetch pipeline kept (29 steps =
//     prologue + 14 unrolled pairs + tail).
// k3: ELIMINATED -- partials reduce folded into k4's prologue.
// k4: per-b block: reduce 251 partial chunks + bias + relu, then W2 matvec
//     + relu, then W3 dot + sigmoid*6-3. Pipeline is now 3 dispatches.

#define B_    128
#define T_    64
#define A1    49
#define V1    49
#define X1    97
#define IJ    2401      // 49*49
#define KTOT  232897    // IJ*97
#define FP    232928    // KTOT padded to multiple of 32
#define PF    128
#define KC2   928       // k2 K-chunk
#define NBLK  251       // 251 * 928 == FP exactly

typedef short s8v __attribute__((ext_vector_type(8)));   // 8 bf16
typedef float f4v __attribute__((ext_vector_type(4)));   // 4 fp32

__device__ __forceinline__ unsigned short f2bf(float f) {
    union { float f; unsigned u; } v; v.f = f;
    return (unsigned short)((v.u + 0x7FFFu + ((v.u >> 16) & 1u)) >> 16); // RNE
}
__device__ __forceinline__ float bf2f(unsigned short h) {
    union { unsigned u; float f; } v; v.u = ((unsigned)h) << 16;
    return v.f;
}

// ---------------- k1: fusion (bf16) -------------------------------------
// grid (4, 128): blockIdx.y = b, blockIdx.x covers 38 ij-tiles of 16 (151 total).
// 512 threads = 8 waves; each wave owns a private 3104B slice in LDS used first
// as the w-operand [16 ij][72 t] then as the output tile [16 ij][97 k].
__global__ __launch_bounds__(512) void k1_fusion(
    const float* __restrict__ audio, const float* __restrict__ video,
    const float* __restrict__ text, unsigned short* __restrict__ fusion)
{
    __shared__ float a_s[T_ * A1];                 // [t][i] f32   12544 B
    __shared__ unsigned short v_s[T_ * V1];        // [t][j] bf16   6272 B
    __shared__ unsigned short xT[112 * 72];        // [k][t] pad72 16128 B
    __shared__ unsigned short w_ws[8][1552];       // per-wave slice 3104 B

    const int b = blockIdx.y;
    const int bx = blockIdx.x;
    const int tid = threadIdx.x;

    for (int idx = tid; idx < T_ * A1; idx += 512) {
        int t = idx / 49, i = idx - t * 49;
        a_s[idx] = (i == 0) ? 1.0f : audio[(b * T_ + t) * 48 + (i - 1)];
        v_s[idx] = f2bf((i == 0) ? 1.0f : video[(b * T_ + t) * 48 + (i - 1)]);
    }
    for (int idx = tid; idx < T_ * X1; idx += 512) {
        int t = idx / 97, k = idx - t * 97;
        xT[k * 72 + t] = f2bf((k == 0) ? 1.0f : text[(b * T_ + t) * 96 + (k - 1)]);
    }
    for (int idx = tid; idx < 15 * 64; idx += 512) {   // zero pad rows k=97..111
        xT[(97 + (idx >> 6)) * 72 + (idx & 63)] = 0;
    }
    if (bx == 0) {                                      // zero fusion pad [KTOT,FP)
        for (int idx = tid; idx < FP - KTOT; idx += 512)
            fusion[(size_t)b * FP + KTOT + idx] = 0;
    }
    __syncthreads();

    const int wave = tid >> 6, lane = tid & 63;
    const int q = lane >> 4, ln = lane & 15;
    unsigned short* w_s = w_ws[wave];

    for (int it = 0; it < 5; ++it) {
        const int tw = it * 8 + wave;          // tile-within-x-block
        if (tw >= 38) break;                   // wave-uniform
        const int tl = bx * 38 + tw;           // global 16-ij tile
        if (tl >= 151) break;
        const int ij0 = tl * 16;

        // w-compute: lane = t, loop over 16 local ij; incremental (i,j)
        {
            int i = ij0 / 49, j = ij0 - (ij0 / 49) * 49;
            #pragma unroll
            for (int ijl = 0; ijl < 16; ++ijl) {
                unsigned short wv = 0;
                if (ij0 + ijl < IJ)
                    wv = f2bf(a_s[lane * 49 + i] * bf2f(v_s[lane * 49 + j]));
                w_s[ijl * 72 + lane] = wv;
                if (++j == 49) { j = 0; ++i; }
            }
        }
        // A-frags: lane holds A[m=ln][t = q*8 + 0..7 (+32)]
        s8v af0 = *(const s8v*)&w_s[ln * 72 + q * 8];
        s8v af1 = *(const s8v*)&w_s[ln * 72 + 32 + q * 8];

        f4v pacc[7];
        #pragma unroll
        for (int nt = 0; nt < 7; ++nt) {
            s8v bf0 = *(const s8v*)&xT[(nt * 16 + ln) * 72 + q * 8];
            s8v bf1 = *(const s8v*)&xT[(nt * 16 + ln) * 72 + 32 + q * 8];
            f4v acc = {0.f, 0.f, 0.f, 0.f};
            acc = __builtin_amdgcn_mfma_f32_16x16x32_bf16(af0, bf0, acc, 0, 0, 0);
            acc = __builtin_amdgcn_mfma_f32_16x16x32_bf16(af1, bf1, acc, 0, 0, 0);
            pacc[nt] = acc;
        }

        // transpose to packed [16 ij][97 k] in the SAME slice (frag data is in
        // regs; writes depend on pacc -> ordered after the reads above).
        #pragma unroll
        for (int nt = 0; nt < 7; ++nt) {
            int kk = nt * 16 + ln;             // C: col=ln -> k, row=q*4+r -> ij
            if (kk < X1) {
                #pragma unroll
                for (int r = 0; r < 4; ++r)
                    w_s[(q * 4 + r) * 97 + kk] = f2bf(pacc[nt][r]);
            }
        }
        asm volatile("s_waitcnt lgkmcnt(0)" ::: "memory");
        __builtin_amdgcn_sched_barrier(0);

        // coalesced copy-out: wave tile = contiguous bytes in fusion.
        // last tile (nv=1): 13 chunks copy 208B >= 194B valid; the 14B overrun
        // lands in the [KTOT,FP) pad (finite bf16 garbage), which k2's
        // p<KTOT W1-guard multiplies by zero.
        const int nv = min(16, IJ - ij0);
        const int bytes = nv * 194;            // nv*97*2
        char* gdst = (char*)(fusion + (size_t)b * FP + (size_t)ij0 * 97);
        const char* lsrc = (const char*)w_s;
        for (int off = lane * 16; off < bytes; off += 1024) {
            uint4 d = *(const uint4*)(lsrc + off);
            *(uint4*)(gdst + off) = d;
        }
    }
}

// ---------------- k2: split-K GEMM h1-partials --------------------------
// 512 threads = 8 waves; wave w owns b-rows [16w, 16w+16). A-frags straight
// from global (fusion row-major == frag layout). W1 staged bf16 in
// double-buffered LDS with a 2-deep prefetch. 251 blocks x 29 steps cover
// FP exactly: perfect balance, no phantom reads.
#define BPAD 40   // LDS row pad (elements)
__global__ __launch_bounds__(512) void k2_gemm(
    const unsigned short* __restrict__ fusion, const float* __restrict__ W1,
    float* __restrict__ partials)
{
    __shared__ unsigned short B_l[2][128 * BPAD];  // [f][p_local], 2 buffers

    const int blk = blockIdx.x;
    const int kbase = blk * KC2;
    const int tid = threadIdx.x;
    const int wave = tid >> 6, lane = tid & 63;
    const int q = lane >> 4, ln = lane & 15;
    const int fB = tid & 127, g = tid >> 7;    // B-stage: thread -> (f, 8-p group)

    const unsigned short* Arow =
        fusion + (size_t)(wave * 16 + ln) * FP + kbase + q * 8;

    f4v acc[8];
    #pragma unroll
    for (int n = 0; n < 8; ++n) acc[n] = (f4v){0.f, 0.f, 0.f, 0.f};

#define LOADW(dst, s)                                                       \
    {                                                                       \
        _Pragma("unroll")                                                   \
        for (int c = 0; c < 8; ++c) {                                       \
            int p = kbase + (s) * 32 + g * 8 + c;                           \
            dst[c] = (p < KTOT) ? W1[(size_t)p * PF + fB] : 0.f;            \
        }                                                                   \
    }
#define PACKW(src, buf)                                                     \
    {                                                                       \
        ushort4 lo, hi;                                                     \
        lo.x = f2bf(src[0]); lo.y = f2bf(src[1]);                           \
        lo.z = f2bf(src[2]); lo.w = f2bf(src[3]);                           \
        hi.x = f2bf(src[4]); hi.y = f2bf(src[5]);                           \
        hi.z = f2bf(src[6]); hi.w = f2bf(src[7]);                           \
        *(ushort4*)&B_l[buf][fB * BPAD + g * 8]     = lo;                   \
        *(ushort4*)&B_l[buf][fB * BPAD + g * 8 + 4] = hi;                   \
    }
#define MFMA8(av, buf)                                                      \
    {                                                                       \
        _Pragma("unroll")                                                   \
        for (int nt = 0; nt < 8; ++nt) {                                    \
            s8v bfv = *(const s8v*)&B_l[buf][(nt * 16 + ln) * BPAD + q * 8];\
            acc[nt] = __builtin_amdgcn_mfma_f32_16x16x32_bf16(              \
                av, bfv, acc[nt], 0, 0, 0);                                 \
        }                                                                   \
    }

    float w0[8], w1[8];
    s8v a0v, a1v;

    // prologue: buf0 <- W(0); issue W(1), A(0)
    LOADW(w0, 0);
    PACKW(w0, 0);
    LOADW(w1, 1);
    a0v = *(const s8v*)Arow;
    __syncthreads();

    // 29 steps = 14 unrolled pairs + tail. Invariant entering iter i:
    //   a0v = A(2i), buf0 = W(2i), w1 = W(2i+1) in regs.
    for (int i = 0; i < 14; ++i) {
        // -- even step s=2i: consume (a0v, buf0)
        LOADW(w0, 2 * i + 2);
        a1v = *(const s8v*)(Arow + (2 * i + 1) * 32);
        MFMA8(a0v, 0);
        PACKW(w1, 1);
        __syncthreads();
        // -- odd step s=2i+1: consume (a1v, buf1)
        if (i < 13) LOADW(w1, 2 * i + 3);      // wave-uniform guard
        a0v = *(const s8v*)(Arow + (2 * i + 2) * 32);
        MFMA8(a1v, 1);
        PACKW(w0, 0);
        __syncthreads();
    }
    MFMA8(a0v, 0);                             // step 28 (last)
#undef LOADW
#undef PACKW
#undef MFMA8

    float* outp = partials + (size_t)blk * (128 * 128);
    #pragma unroll
    for (int nt = 0; nt < 8; ++nt) {
        const int f = nt * 16 + ln;
        #pragma unroll
        for (int r = 0; r < 4; ++r)
            outp[(wave * 16 + q * 4 + r) * 128 + f] = acc[nt][r];
    }
}

// ---------------- k4: reduce + bias + relu + MLP tail -------------------
// grid 128 blocks (one per b) x 256 thr. Prologue reduces this b's row over
// the 251 partial chunks (2-way r-split), then bias+relu -> hrow, then
// h2 = relu(hrow@W2+b2), out = sigmoid(h2@W3+b3)*6-3.
__global__ __launch_bounds__(256) void k4_out(
    const float* __restrict__ partials, const float* __restrict__ b1,
    const float* __restrict__ W2, const float* __restrict__ b2,
    const float* __restrict__ W3, const float* __restrict__ b3,
    float* __restrict__ out)
{
    __shared__ float red[256];
    __shared__ float hrow[128];
    __shared__ float red2[2];
    const int b = blockIdx.x, tid = threadIdx.x;
    const int f = tid & 127, rh = tid >> 7;

    float s = 0.f;
    #pragma unroll 4
    for (int r = rh; r < NBLK; r += 2)
        s += partials[(size_t)r * 16384 + b * 128 + f];
    red[tid] = s;
    __syncthreads();
    if (tid < 128)
        hrow[f] = fmaxf(red[f] + red[f + 128] + b1[f], 0.f);
    __syncthreads();
    if (tid < 128) {
        float s2 = b2[f];
        #pragma unroll 8
        for (int c = 0; c < 128; ++c) s2 += hrow[c] * W2[c * 128 + f];
        float p = fmaxf(s2, 0.f) * W3[f];
        #pragma unroll
        for (int off = 32; off; off >>= 1) p += __shfl_down(p, off, 64);
        if ((f & 63) == 0) red2[f >> 6] = p;
    }
    __syncthreads();
    if (tid == 0) {
        float t = red2[0] + red2[1] + b3[0];
        out[b] = 6.0f / (1.0f + expf(-t)) - 3.0f;
    }
}

extern "C" void kernel_launch(void* const* d_in, const int* in_sizes, int n_in,
                              void* d_out, int out_size, void* d_ws, size_t ws_size,
                              hipStream_t stream)
{
    const float* audio = (const float*)d_in[0];
    const float* video = (const float*)d_in[1];
    const float* text  = (const float*)d_in[2];
    const float* W1 = (const float*)d_in[3];
    const float* b1 = (const float*)d_in[4];
    const float* W2 = (const float*)d_in[5];
    const float* b2 = (const float*)d_in[6];
    const float* W3 = (const float*)d_in[7];
    const float* b3 = (const float*)d_in[8];
    float* out = (float*)d_out;

    // ws layout: fusion bf16 [128][FP] = 59,629,568 B
    //            partials fp32 [251][16384] = 16,449,536 B @ 59,629,568
    //            total 76,079,104 B
    char* ws = (char*)d_ws;
    unsigned short* fusion = (unsigned short*)ws;
    float* partials = (float*)(ws + 59629568);

    k1_fusion<<<dim3(4, 128), 512, 0, stream>>>(audio, video, text, fusion);
    k2_gemm<<<dim3(NBLK), 512, 0, stream>>>(fusion, W1, partials);
    k4_out<<<dim3(128), 256, 0, stream>>>(partials, b1, W2, b2, W3, b3, out);
}

// Round 5
// 246.687 us; speedup vs baseline: 1.0436x; 1.0033x over previous
//
#include <hip/hip_runtime.h>

// Tensor Fusion Network, MI355X. Round 6 (resubmit — R4 bench was an infra
// failure: container acquisition, not kernel).
// k1: fusion[b][p] bf16 via per-wave MFMA (unchanged).
// k2: split-K GEMM, KC=928, 251 blocks (= FP exactly), 2-deep W1 prefetch.
//     partials stored [b][blk][f] -- same write cost (sector-aligned 64B
//     groups), makes k4's reduce a contiguous per-b stream.
// k4: 512 thr, 8-way chunk-split, float2 coalesced reads of the contiguous
//     partials row, then bias+relu + W2 matvec + W3 dot + sigmoid.

#define B_    128
#define T_    64
#define A1    49
#define V1    49
#define X1    97
#define IJ    2401      // 49*49
#define KTOT  232897    // IJ*97
#define FP    232928    // KTOT padded to multiple of 32
#define PF    128
#define KC2   928       // k2 K-chunk
#define NBLK  251       // 251 * 928 == FP exactly
#define PROW  (NBLK * 128)   // partials row stride per b = 32128

typedef short s8v __attribute__((ext_vector_type(8)));   // 8 bf16
typedef float f4v __attribute__((ext_vector_type(4)));   // 4 fp32

__device__ __forceinline__ unsigned short f2bf(float f) {
    union { float f; unsigned u; } v; v.f = f;
    return (unsigned short)((v.u + 0x7FFFu + ((v.u >> 16) & 1u)) >> 16); // RNE
}
__device__ __forceinline__ float bf2f(unsigned short h) {
    union { unsigned u; float f; } v; v.u = ((unsigned)h) << 16;
    return v.f;
}

// ---------------- k1: fusion (bf16) -------------------------------------
// grid (4, 128): blockIdx.y = b, blockIdx.x covers 38 ij-tiles of 16 (151 total).
// 512 threads = 8 waves; each wave owns a private 3104B slice in LDS used first
// as the w-operand [16 ij][72 t] then as the output tile [16 ij][97 k].
__global__ __launch_bounds__(512) void k1_fusion(
    const float* __restrict__ audio, const float* __restrict__ video,
    const float* __restrict__ text, unsigned short* __restrict__ fusion)
{
    __shared__ float a_s[T_ * A1];                 // [t][i] f32   12544 B
    __shared__ unsigned short v_s[T_ * V1];        // [t][j] bf16   6272 B
    __shared__ unsigned short xT[112 * 72];        // [k][t] pad72 16128 B
    __shared__ unsigned short w_ws[8][1552];       // per-wave slice 3104 B

    const int b = blockIdx.y;
    const int bx = blockIdx.x;
    const int tid = threadIdx.x;

    for (int idx = tid; idx < T_ * A1; idx += 512) {
        int t = idx / 49, i = idx - t * 49;
        a_s[idx] = (i == 0) ? 1.0f : audio[(b * T_ + t) * 48 + (i - 1)];
        v_s[idx] = f2bf((i == 0) ? 1.0f : video[(b * T_ + t) * 48 + (i - 1)]);
    }
    for (int idx = tid; idx < T_ * X1; idx += 512) {
        int t = idx / 97, k = idx - t * 97;
        xT[k * 72 + t] = f2bf((k == 0) ? 1.0f : text[(b * T_ + t) * 96 + (k - 1)]);
    }
    for (int idx = tid; idx < 15 * 64; idx += 512) {   // zero pad rows k=97..111
        xT[(97 + (idx >> 6)) * 72 + (idx & 63)] = 0;
    }
    if (bx == 0) {                                      // zero fusion pad [KTOT,FP)
        for (int idx = tid; idx < FP - KTOT; idx += 512)
            fusion[(size_t)b * FP + KTOT + idx] = 0;
    }
    __syncthreads();

    const int wave = tid >> 6, lane = tid & 63;
    const int q = lane >> 4, ln = lane & 15;
    unsigned short* w_s = w_ws[wave];

    for (int it = 0; it < 5; ++it) {
        const int tw = it * 8 + wave;          // tile-within-x-block
        if (tw >= 38) break;                   // wave-uniform
        const int tl = bx * 38 + tw;           // global 16-ij tile
        if (tl >= 151) break;
        const int ij0 = tl * 16;

        // w-compute: lane = t, loop over 16 local ij; incremental (i,j)
        {
            int i = ij0 / 49, j = ij0 - (ij0 / 49) * 49;
            #pragma unroll
            for (int ijl = 0; ijl < 16; ++ijl) {
                unsigned short wv = 0;
                if (ij0 + ijl < IJ)
                    wv = f2bf(a_s[lane * 49 + i] * bf2f(v_s[lane * 49 + j]));
                w_s[ijl * 72 + lane] = wv;
                if (++j == 49) { j = 0; ++i; }
            }
        }
        // A-frags: lane holds A[m=ln][t = q*8 + 0..7 (+32)]
        s8v af0 = *(const s8v*)&w_s[ln * 72 + q * 8];
        s8v af1 = *(const s8v*)&w_s[ln * 72 + 32 + q * 8];

        f4v pacc[7];
        #pragma unroll
        for (int nt = 0; nt < 7; ++nt) {
            s8v bf0 = *(const s8v*)&xT[(nt * 16 + ln) * 72 + q * 8];
            s8v bf1 = *(const s8v*)&xT[(nt * 16 + ln) * 72 + 32 + q * 8];
            f4v acc = {0.f, 0.f, 0.f, 0.f};
            acc = __builtin_amdgcn_mfma_f32_16x16x32_bf16(af0, bf0, acc, 0, 0, 0);
            acc = __builtin_amdgcn_mfma_f32_16x16x32_bf16(af1, bf1, acc, 0, 0, 0);
            pacc[nt] = acc;
        }

        // transpose to packed [16 ij][97 k] in the SAME slice (frag data is in
        // regs; writes depend on pacc -> ordered after the reads above).
        #pragma unroll
        for (int nt = 0; nt < 7; ++nt) {
            int kk = nt * 16 + ln;             // C: col=ln -> k, row=q*4+r -> ij
            if (kk < X1) {
                #pragma unroll
                for (int r = 0; r < 4; ++r)
                    w_s[(q * 4 + r) * 97 + kk] = f2bf(pacc[nt][r]);
            }
        }
        asm volatile("s_waitcnt lgkmcnt(0)" ::: "memory");
        __builtin_amdgcn_sched_barrier(0);

        // coalesced copy-out: wave tile = contiguous bytes in fusion.
        // last tile (nv=1): 13 chunks copy 208B >= 194B valid; the 14B overrun
        // lands in the [KTOT,FP) pad (finite bf16 garbage), which k2's
        // p<KTOT W1-guard multiplies by zero.
        const int nv = min(16, IJ - ij0);
        const int bytes = nv * 194;            // nv*97*2
        char* gdst = (char*)(fusion + (size_t)b * FP + (size_t)ij0 * 97);
        const char* lsrc = (const char*)w_s;
        for (int off = lane * 16; off < bytes; off += 1024) {
            uint4 d = *(const uint4*)(lsrc + off);
            *(uint4*)(gdst + off) = d;
        }
    }
}

// ---------------- k2: split-K GEMM h1-partials --------------------------
// 512 threads = 8 waves; wave w owns b-rows [16w, 16w+16). A-frags straight
// from global (fusion row-major == frag layout). W1 staged bf16 in
// double-buffered LDS with a 2-deep prefetch. 251 blocks x 29 steps cover
// FP exactly. Output layout: partials[b][blk][f].
#define BPAD 40   // LDS row pad (elements)
__global__ __launch_bounds__(512) void k2_gemm(
    const unsigned short* __restrict__ fusion, const float* __restrict__ W1,
    float* __restrict__ partials)
{
    __shared__ unsigned short B_l[2][128 * BPAD];  // [f][p_local], 2 buffers

    const int blk = blockIdx.x;
    const int kbase = blk * KC2;
    const int tid = threadIdx.x;
    const int wave = tid >> 6, lane = tid & 63;
    const int q = lane >> 4, ln = lane & 15;
    const int fB = tid & 127, g = tid >> 7;    // B-stage: thread -> (f, 8-p group)

    const unsigned short* Arow =
        fusion + (size_t)(wave * 16 + ln) * FP + kbase + q * 8;

    f4v acc[8];
    #pragma unroll
    for (int n = 0; n < 8; ++n) acc[n] = (f4v){0.f, 0.f, 0.f, 0.f};

#define LOADW(dst, s)                                                       \
    {                                                                       \
        _Pragma("unroll")                                                   \
        for (int c = 0; c < 8; ++c) {                                       \
            int p = kbase + (s) * 32 + g * 8 + c;                           \
            dst[c] = (p < KTOT) ? W1[(size_t)p * PF + fB] : 0.f;            \
        }                                                                   \
    }
#define PACKW(src, buf)                                                     \
    {                                                                       \
        ushort4 lo, hi;                                                     \
        lo.x = f2bf(src[0]); lo.y = f2bf(src[1]);                           \
        lo.z = f2bf(src[2]); lo.w = f2bf(src[3]);                           \
        hi.x = f2bf(src[4]); hi.y = f2bf(src[5]);                           \
        hi.z = f2bf(src[6]); hi.w = f2bf(src[7]);                           \
        *(ushort4*)&B_l[buf][fB * BPAD + g * 8]     = lo;                   \
        *(ushort4*)&B_l[buf][fB * BPAD + g * 8 + 4] = hi;                   \
    }
#define MFMA8(av, buf)                                                      \
    {                                                                       \
        _Pragma("unroll")                                                   \
        for (int nt = 0; nt < 8; ++nt) {                                    \
            s8v bfv = *(const s8v*)&B_l[buf][(nt * 16 + ln) * BPAD + q * 8];\
            acc[nt] = __builtin_amdgcn_mfma_f32_16x16x32_bf16(              \
                av, bfv, acc[nt], 0, 0, 0);                                 \
        }                                                                   \
    }

    float w0[8], w1[8];
    s8v a0v, a1v;

    // prologue: buf0 <- W(0); issue W(1), A(0)
    LOADW(w0, 0);
    PACKW(w0, 0);
    LOADW(w1, 1);
    a0v = *(const s8v*)Arow;
    __syncthreads();

    // 29 steps = 14 unrolled pairs + tail. Invariant entering iter i:
    //   a0v = A(2i), buf0 = W(2i), w1 = W(2i+1) in regs.
    for (int i = 0; i < 14; ++i) {
        // -- even step s=2i: consume (a0v, buf0)
        LOADW(w0, 2 * i + 2);
        a1v = *(const s8v*)(Arow + (2 * i + 1) * 32);
        MFMA8(a0v, 0);
        PACKW(w1, 1);
        __syncthreads();
        // -- odd step s=2i+1: consume (a1v, buf1)
        if (i < 13) LOADW(w1, 2 * i + 3);      // wave-uniform guard
        a0v = *(const s8v*)(Arow + (2 * i + 2) * 32);
        MFMA8(a1v, 1);
        PACKW(w0, 0);
        __syncthreads();
    }
    MFMA8(a0v, 0);                             // step 28 (last)
#undef LOADW
#undef PACKW
#undef MFMA8

    // store: partials[b][blk][f], b = wave*16 + q*4 + r
    #pragma unroll
    for (int nt = 0; nt < 8; ++nt) {
        const int f = nt * 16 + ln;
        #pragma unroll
        for (int r = 0; r < 4; ++r)
            partials[(size_t)(wave * 16 + q * 4 + r) * PROW + blk * 128 + f] =
                acc[nt][r];
    }
}

// ---------------- k4: reduce + bias + relu + MLP tail -------------------
// grid 128 blocks (one per b) x 512 thr. Prologue reduces this b's contiguous
// partials row (251 chunks, 8-way split, float2 coalesced loads), then
// bias+relu -> hrow, h2 = relu(hrow@W2+b2), out = sigmoid(h2@W3+b3)*6-3.
__global__ __launch_bounds__(512) void k4_out(
    const float* __restrict__ partials, const float* __restrict__ b1,
    const float* __restrict__ W2, const float* __restrict__ b2,
    const float* __restrict__ W3, const float* __restrict__ b3,
    float* __restrict__ out)
{
    __shared__ float red[8 * 128];
    __shared__ float hrow[128];
    __shared__ float red2[2];
    const int b = blockIdx.x, tid = threadIdx.x;
    const int f2 = (tid & 63) * 2, grp = tid >> 6;   // grp 0..7

    const float* pb = partials + (size_t)b * PROW;
    float s0 = 0.f, s1 = 0.f;
    for (int r = grp; r < NBLK; r += 8) {
        float2 v = *(const float2*)&pb[r * 128 + f2];
        s0 += v.x; s1 += v.y;
    }
    red[grp * 128 + f2]     = s0;
    red[grp * 128 + f2 + 1] = s1;
    __syncthreads();

    if (tid < 128) {
        float v = 0.f;
        #pragma unroll
        for (int g = 0; g < 8; ++g) v += red[g * 128 + tid];
        hrow[tid] = fmaxf(v + b1[tid], 0.f);
    }
    __syncthreads();

    if (tid < 128) {
        const int f = tid;
        float s2 = b2[f];
        #pragma unroll 8
        for (int c = 0; c < 128; ++c) s2 += hrow[c] * W2[c * 128 + f];
        float p = fmaxf(s2, 0.f) * W3[f];
        #pragma unroll
        for (int off = 32; off; off >>= 1) p += __shfl_down(p, off, 64);
        if ((f & 63) == 0) red2[f >> 6] = p;
    }
    __syncthreads();
    if (tid == 0) {
        float t = red2[0] + red2[1] + b3[0];
        out[b] = 6.0f / (1.0f + expf(-t)) - 3.0f;
    }
}

extern "C" void kernel_launch(void* const* d_in, const int* in_sizes, int n_in,
                              void* d_out, int out_size, void* d_ws, size_t ws_size,
                              hipStream_t stream)
{
    const float* audio = (const float*)d_in[0];
    const float* video = (const float*)d_in[1];
    const float* text  = (const float*)d_in[2];
    const float* W1 = (const float*)d_in[3];
    const float* b1 = (const float*)d_in[4];
    const float* W2 = (const float*)d_in[5];
    const float* b2 = (const float*)d_in[6];
    const float* W3 = (const float*)d_in[7];
    const float* b3 = (const float*)d_in[8];
    float* out = (float*)d_out;

    // ws layout: fusion bf16 [128][FP] = 59,629,568 B
    //            partials fp32 [128][PROW] = 16,449,536 B @ 59,629,568
    //            total 76,079,104 B
    char* ws = (char*)d_ws;
    unsigned short* fusion = (unsigned short*)ws;
    float* partials = (float*)(ws + 59629568);

    k1_fusion<<<dim3(4, 128), 512, 0, stream>>>(audio, video, text, fusion);
    k2_gemm<<<dim3(NBLK), 512, 0, stream>>>(fusion, W1, partials);
    k4_out<<<dim3(128), 512, 0, stream>>>(partials, b1, W2, b2, W3, b3, out);
}